// Round 1
// baseline (1486.711 us; speedup 1.0000x reference)
//
#include <hip/hip_runtime.h>
#include <hip/hip_bf16.h>

// Problem constants: B=4, S=2048, IN=2048, OUT=2048, ID=64
#define M_DIM 8192   // B*S
#define N_DIM 2048   // OUT
#define K_DIM 2048   // IN

#define BM 128
#define BN 128
#define BK 32

typedef __bf16 bf16x8 __attribute__((ext_vector_type(8)));
typedef float  floatx4 __attribute__((ext_vector_type(4)));

// ---------- helpers ----------

__device__ __forceinline__ unsigned short f2bf(float f) {
    unsigned int u = __builtin_bit_cast(unsigned int, f);
    u += 0x7fffu + ((u >> 16) & 1u);       // round-to-nearest-even
    return (unsigned short)(u >> 16);
}

// async global->LDS, 16B per lane. LDS dest is wave-uniform base + lane*16,
// so lds ptr must be computed as base + lane*16 in lane order (it is below).
__device__ __forceinline__ void gld_lds16(const void* g, void* l) {
    __builtin_amdgcn_global_load_lds(
        (__attribute__((address_space(1))) unsigned int*)g,
        (__attribute__((address_space(3))) unsigned int*)l,
        16 /*size*/, 0 /*offset*/, 0 /*aux*/);
}

// ---------- kernel 1: x fp32 -> bf16 (16,777,216 elems, 8/thread) ----------

__global__ __launch_bounds__(256) void cvt_x_bf16(const float* __restrict__ x,
                                                  unsigned short* __restrict__ y) {
    long i = ((long)blockIdx.x * 256 + threadIdx.x) * 8;
    float4 a = *(const float4*)(x + i);
    float4 b = *(const float4*)(x + i + 4);
    uint4 o;
    o.x = (unsigned)f2bf(a.x) | ((unsigned)f2bf(a.y) << 16);
    o.y = (unsigned)f2bf(a.z) | ((unsigned)f2bf(a.w) << 16);
    o.z = (unsigned)f2bf(b.x) | ((unsigned)f2bf(b.y) << 16);
    o.w = (unsigned)f2bf(b.z) | ((unsigned)f2bf(b.w) << 16);
    *(uint4*)(y + i) = o;
}

// ---------- kernel 2: W[row] = dot(P_w[row,0:64], coef) -> bf16 ----------
// 16 lanes per row, one float4 per lane, fully coalesced (t*16 bytes),
// shfl_xor reduce over 16 lanes. 512 rows per block, 32 iters.

__global__ __launch_bounds__(256) void rowdot_w(const float* __restrict__ P,
                                                const float* __restrict__ coef,
                                                unsigned short* __restrict__ outw) {
    const int t = threadIdx.x;
    const int j = t & 15;
    const float4 c = *(const float4*)(coef + j * 4);
    const long row0 = (long)blockIdx.x * 512 + (t >> 4);
    #pragma unroll 4
    for (int it = 0; it < 32; ++it) {
        long row = row0 + (long)it * 16;
        float4 p = *(const float4*)(P + row * 64 + j * 4);
        float s = p.x * c.x + p.y * c.y + p.z * c.z + p.w * c.w;
        s += __shfl_xor(s, 1);
        s += __shfl_xor(s, 2);
        s += __shfl_xor(s, 4);
        s += __shfl_xor(s, 8);
        if (j == 0) outw[row] = f2bf(s);
    }
}

// ---------- kernel 3: b = P_b @ bias_coef (2048 rows) -> fp32 ----------

__global__ __launch_bounds__(256) void rowdot_b(const float* __restrict__ P,
                                                const float* __restrict__ coef,
                                                float* __restrict__ outb) {
    const int t = threadIdx.x;
    const int j = t & 15;
    const int row = blockIdx.x * 16 + (t >> 4);
    float4 c = *(const float4*)(coef + j * 4);
    float4 p = *(const float4*)(P + (long)row * 64 + j * 4);
    float s = p.x * c.x + p.y * c.y + p.z * c.z + p.w * c.w;
    s += __shfl_xor(s, 1);
    s += __shfl_xor(s, 2);
    s += __shfl_xor(s, 4);
    s += __shfl_xor(s, 8);
    if (j == 0) outb[row] = s;
}

// ---------- kernel 4: C[M,N] = A[M,K] * B[N,K]^T + bias, bf16 MFMA ----------
// m97 structure: 128x128 tile, BK=32, 256 threads = 4 waves in 2x2,
// each wave a 64x64 quadrant = 4x4 tiles of 16x16x32 MFMA.

__global__ __launch_bounds__(256) void gemm_bt(const __bf16* __restrict__ A,
                                               const __bf16* __restrict__ Bm,
                                               const float* __restrict__ bias,
                                               float* __restrict__ C) {
    __shared__ __align__(16) __bf16 As[BM * BK];   // 8 KiB
    __shared__ __align__(16) __bf16 Bs[BN * BK];   // 8 KiB

    const int t    = threadIdx.x;
    const int lane = t & 63;
    const int w    = t >> 6;
    const int wm   = w >> 1;           // 0..1
    const int wn   = w & 1;            // 0..1
    const int bm   = blockIdx.y * BM;
    const int bn   = blockIdx.x * BN;

    // staging chunks: tile is 512 x 16B chunks; chunk = i*256 + t
    // row = chunk>>2, seg = chunk&3 -> global (row, seg*8) of the k-slab
    const int c0 = t, c1 = 256 + t;
    const int r0 = c0 >> 2, s0 = c0 & 3;
    const int r1 = c1 >> 2, s1 = c1 & 3;

    const __bf16* Ag0 = A + (long)(bm + r0) * K_DIM + s0 * 8;
    const __bf16* Ag1 = A + (long)(bm + r1) * K_DIM + s1 * 8;
    const __bf16* Bg0 = Bm + (long)(bn + r0) * K_DIM + s0 * 8;
    const __bf16* Bg1 = Bm + (long)(bn + r1) * K_DIM + s1 * 8;
    __bf16* Al0 = As + c0 * 8;
    __bf16* Al1 = As + c1 * 8;
    __bf16* Bl0 = Bs + c0 * 8;
    __bf16* Bl1 = Bs + c1 * 8;

    floatx4 acc[4][4] = {};

    const int fr = lane & 15;          // row-in-16 for A, col-in-16 for B
    const int q  = lane >> 4;          // k-quad: k = q*8 + j
    const int arow = wm * 64 + fr;
    const int brow = wn * 64 + fr;

    for (int kk = 0; kk < K_DIM; kk += BK) {
        gld_lds16(Ag0 + kk, Al0);
        gld_lds16(Ag1 + kk, Al1);
        gld_lds16(Bg0 + kk, Bl0);
        gld_lds16(Bg1 + kk, Bl1);
        __syncthreads();               // drains vmcnt: LDS tile ready

        bf16x8 af[4], bfr[4];
        #pragma unroll
        for (int mt = 0; mt < 4; ++mt)
            af[mt] = *(const bf16x8*)(As + (arow + mt * 16) * BK + q * 8);
        #pragma unroll
        for (int nt = 0; nt < 4; ++nt)
            bfr[nt] = *(const bf16x8*)(Bs + (brow + nt * 16) * BK + q * 8);

        #pragma unroll
        for (int mt = 0; mt < 4; ++mt)
            #pragma unroll
            for (int nt = 0; nt < 4; ++nt)
                acc[mt][nt] = __builtin_amdgcn_mfma_f32_16x16x32_bf16(
                    af[mt], bfr[nt], acc[mt][nt], 0, 0, 0);

        __syncthreads();               // all frag reads done before restage
    }

    // epilogue: C/D layout col = lane&15, row = (lane>>4)*4 + reg
    const int col0  = bn + wn * 64 + (lane & 15);
    const int rquad = (lane >> 4) * 4;
    float bv[4];
    #pragma unroll
    for (int nt = 0; nt < 4; ++nt) bv[nt] = bias[col0 + nt * 16];

    #pragma unroll
    for (int mt = 0; mt < 4; ++mt) {
        int row = bm + wm * 64 + mt * 16 + rquad;
        #pragma unroll
        for (int nt = 0; nt < 4; ++nt) {
            int col = col0 + nt * 16;
            float* cp = C + (long)row * N_DIM + col;
            #pragma unroll
            for (int r = 0; r < 4; ++r)
                cp[(long)r * N_DIM] = acc[mt][nt][r] + bv[nt];
        }
    }
}

// ---------- launch ----------

extern "C" void kernel_launch(void* const* d_in, const int* in_sizes, int n_in,
                              void* d_out, int out_size, void* d_ws, size_t ws_size,
                              hipStream_t stream) {
    const float* x   = (const float*)d_in[0];   // [8192, 2048]
    const float* P_w = (const float*)d_in[1];   // [4194304, 64]
    const float* P_b = (const float*)d_in[2];   // [2048, 64]
    const float* wc  = (const float*)d_in[3];   // [64]
    const float* bc  = (const float*)d_in[4];   // [64]
    float* out = (float*)d_out;                 // [8192, 2048]

    char* ws = (char*)d_ws;
    unsigned short* xbf = (unsigned short*)ws;                     // 32 MiB
    unsigned short* Wbf = (unsigned short*)(ws + 33554432);        // 8 MiB
    float*          bb  = (float*)(ws + 33554432 + 8388608);       // 8 KiB

    // 1) x -> bf16 : 16,777,216 / 8 per thread / 256 = 8192 blocks
    cvt_x_bf16<<<8192, 256, 0, stream>>>(x, xbf);
    // 2) W -> bf16 : 4,194,304 rows / 512 per block = 8192 blocks
    rowdot_w<<<8192, 256, 0, stream>>>(P_w, wc, Wbf);
    // 3) bias : 2048 rows / 16 per block = 128 blocks
    rowdot_b<<<128, 256, 0, stream>>>(P_b, bc, bb);
    // 4) GEMM: grid (N/128, M/128) = (16, 64)
    gemm_bt<<<dim3(N_DIM / BN, M_DIM / BM), 256, 0, stream>>>(
        (const __bf16*)xbf, (const __bf16*)Wbf, bb, out);
}